// Round 6
// baseline (232.559 us; speedup 1.0000x reference)
//
#include <hip/hip_runtime.h>

#define NROWS 65536
#define DIM 64
#define KCODES 8192
#define DECAYF 0.99f
#define EPSV 1e-5f
#define KD (KCODES * DIM)
#define KSPLIT 4
#define KC (KCODES / KSPLIT)   // 2048 codes per split chunk
#define ROUNDS (KC / 128)      // 16 rounds x 128 codes (16 KB) per chunk

typedef _Float16 half8 __attribute__((ext_vector_type(8)));
typedef float f32x16 __attribute__((ext_vector_type(16)));

// ws layout (float offsets) — total ~3.9 MB
#define WS_STATS  0          // 256: mean[64], rstd[64], running_std[64]
#define WS_NHCK   256        // 8192: -0.5*||e_k||^2
#define WS_EBUF   8448       // 262144: 8192 codes x 64 dims f16 (1 MB), staged layout
#define WS_PSUM   270592     // 16384
#define WS_PSQ    286976     // 16384
#define WS_PACKED 303360     // 131072 floats = 65536 u64 (key<<32 | 8191-code)
#define WS_DW     434432     // 8192*64
#define WS_COUNTS 958720     // 8192  (PACKED..COUNTS contiguous: single memset)

// ---------------- K1a: per-block column partial sums ----------------
__global__ __launch_bounds__(256) void k_colstats_partial(
    const float* __restrict__ x, float* __restrict__ psum, float* __restrict__ psq)
{
    const int wave = threadIdx.x >> 6;
    const int col  = threadIdx.x & 63;
    const int base = blockIdx.x * 256;
    float s = 0.f, q = 0.f;
    #pragma unroll 4
    for (int i = 0; i < 64; ++i) {
        int r = base + i * 4 + wave;
        float v = x[(size_t)r * DIM + col];
        s += v;
        q += v * v;
    }
    __shared__ float ls[4][64];
    __shared__ float lq[4][64];
    ls[wave][col] = s;
    lq[wave][col] = q;
    __syncthreads();
    if (threadIdx.x < 64) {
        psum[blockIdx.x * 64 + col] = ls[0][col] + ls[1][col] + ls[2][col] + ls[3][col];
        psq[blockIdx.x * 64 + col]  = lq[0][col] + lq[1][col] + lq[2][col] + lq[3][col];
    }
}

// ---------------- K1b: finalize stats ----------------
__global__ void k_colstats_final(const float* __restrict__ psum,
                                 const float* __restrict__ psq,
                                 float* __restrict__ stats)
{
    const int col = threadIdx.x; // 64 threads
    float s = 0.f, q = 0.f;
    for (int i = 0; i < 256; ++i) {
        s += psum[i * 64 + col];
        q += psq[i * 64 + col];
    }
    const float n = (float)NROWS;
    float mean = s / n;
    float var = q / n - mean * mean;
    if (var < 0.f) var = 0.f;
    stats[col]       = mean;
    stats[64 + col]  = 1.0f / sqrtf(var + EPSV);
    stats[128 + col] = sqrtf(var * (n / (n - 1.0f)) + EPSV);
}

// ---------------- K2: prep emb (f16 centered plane, staged layout) + nhck --
// ebuf layout (half8 units): idx = R128*1024 + t*256 + c*64 + h*32 + col
//   code = R128*128 + t*32 + col ; element dims = c*16 + h*8 + j
__global__ __launch_bounds__(256) void k_prep(const float* __restrict__ emb,
                                              half8* __restrict__ ebuf,
                                              float* __restrict__ nhck)
{
    const int tid = blockIdx.x * 256 + threadIdx.x;   // 65536 = 8192 codes * 8
    const int code = tid >> 3, sub = tid & 7;
    const int c = sub >> 1, h = sub & 1;
    const int d0 = c * 16 + h * 8;
    const float* e = emb + (size_t)code * DIM + d0;
    float4 a = *(const float4*)e;
    float4 b = *(const float4*)(e + 4);
    float f[8] = {a.x, a.y, a.z, a.w, b.x, b.y, b.z, b.w};
    half8 hh;
    float ssq = 0.f;
    #pragma unroll
    for (int i = 0; i < 8; ++i) {
        hh[i] = (_Float16)(f[i] - 0.5f);   // centered: halves f16 quantization err
        ssq += f[i] * f[i];
    }
    #pragma unroll
    for (int o = 1; o < 8; o <<= 1) ssq += __shfl_xor(ssq, o, 64);
    if (sub == 0) nhck[code] = -0.5f * ssq;
    const int R = code >> 7, t = (code >> 5) & 3, col = code & 31;
    ebuf[(size_t)R * 1024 + t * 256 + c * 64 + h * 32 + col] = hh;
}

// ---------------- K3: 32x32 MFMA distance argmin ----------------
__device__ __forceinline__ void gload16(const void* g, void* l)
{
    __builtin_amdgcn_global_load_lds(
        (const __attribute__((address_space(1))) void*)g,
        (__attribute__((address_space(3))) void*)l, 16, 0, 0);
}

// 512 thr = 8 waves; wave owns 32 rows; block = 256 rows x KC codes.
// grid = (NROWS/256, KSPLIT) = 1024 blocks = exactly 4/CU (32 waves/CU).
// Maximizes w = xn.(e-0.5) + nhck (== argmin dist).
// NOTE: no min-waves clause — (256,5) in round 4 forced VGPR 64->48 and
// spilled ~5 GB/dispatch. Natural allocation is 64 VGPR = 8 waves/SIMD.
__global__ __launch_bounds__(512) void k_argmin32(
    const float* __restrict__ x, const half8* __restrict__ ebuf,
    const float* __restrict__ nhckg, const float* __restrict__ stats,
    unsigned long long* __restrict__ packed)
{
    __shared__ half8 smem[2048];   // 32 KB: 2 x 16 KB rounds

    const int lane = threadIdx.x & 63;
    const int wave = threadIdx.x >> 6;
    const int kc = blockIdx.y;
    const int col = lane & 31, h = lane >> 5;
    const int myrow = blockIdx.x * 256 + wave * 32 + col;

    // ---- A fragments: xh (f16) + xm (residual, unscaled f16) ----
    half8 ah[4], am[4];
    {
        const float* xr = x + (size_t)myrow * DIM + h * 8;
        #pragma unroll
        for (int c = 0; c < 4; ++c) {
            float4 v0  = *(const float4*)(xr + c * 16);
            float4 v1  = *(const float4*)(xr + c * 16 + 4);
            float4 mu0 = *(const float4*)(stats + h * 8 + c * 16);
            float4 mu1 = *(const float4*)(stats + h * 8 + c * 16 + 4);
            float4 sg0 = *(const float4*)(stats + 64 + h * 8 + c * 16);
            float4 sg1 = *(const float4*)(stats + 64 + h * 8 + c * 16 + 4);
            float xn[8] = {(v0.x - mu0.x) * sg0.x, (v0.y - mu0.y) * sg0.y,
                           (v0.z - mu0.z) * sg0.z, (v0.w - mu0.w) * sg0.w,
                           (v1.x - mu1.x) * sg1.x, (v1.y - mu1.y) * sg1.y,
                           (v1.z - mu1.z) * sg1.z, (v1.w - mu1.w) * sg1.w};
            #pragma unroll
            for (int j = 0; j < 8; ++j) {
                _Float16 t = (_Float16)xn[j];
                ah[c][j] = t;
                am[c][j] = (_Float16)(xn[j] - (float)t);
            }
        }
    }

    float best[16];
    int bcode[16];
    #pragma unroll
    for (int i = 0; i < 16; ++i) { best[i] = -3.4e38f; bcode[i] = 0; }

    const half8* esrc = ebuf + (size_t)kc * (KC * 8);   // 8 half8 per code
    const float* ckb = nhckg + kc * KC;

    // prologue stage (512 thr x 16 B x 2 = 16 KB) + first-round ck prefetch
    {
        const char* src = (const char*)esrc + threadIdx.x * 16;
        char* dst = (char*)smem + threadIdx.x * 16;
        #pragma unroll
        for (int i = 0; i < 2; ++i) gload16(src + i * 8192, dst + i * 8192);
    }
    float nhck[4];
    #pragma unroll
    for (int t = 0; t < 4; ++t) nhck[t] = ckb[t * 32 + col];
    __syncthreads();

    for (int R = 0; R < ROUNDS; ++R) {
        const int buf = R & 1;
        float nhck_n[4] = {0.f, 0.f, 0.f, 0.f};
        if (R < ROUNDS - 1) {
            const char* src = (const char*)esrc + (size_t)(R + 1) * 16384 + threadIdx.x * 16;
            char* dst = (char*)smem + (buf ^ 1) * 16384 + threadIdx.x * 16;
            #pragma unroll
            for (int i = 0; i < 2; ++i) gload16(src + i * 8192, dst + i * 8192);
            #pragma unroll
            for (int t = 0; t < 4; ++t) nhck_n[t] = ckb[(R + 1) * 128 + t * 32 + col];
        }

        const half8* sb = smem + buf * 1024 + lane;
        #pragma unroll
        for (int t = 0; t < 4; ++t) {
            half8 b0 = sb[t * 256];
            half8 b1 = sb[t * 256 + 64];
            half8 b2 = sb[t * 256 + 128];
            half8 b3 = sb[t * 256 + 192];
            f32x16 acc;
            #pragma unroll
            for (int i = 0; i < 16; ++i) acc[i] = nhck[t];
            acc = __builtin_amdgcn_mfma_f32_32x32x16_f16(ah[0], b0, acc, 0, 0, 0);
            acc = __builtin_amdgcn_mfma_f32_32x32x16_f16(ah[1], b1, acc, 0, 0, 0);
            acc = __builtin_amdgcn_mfma_f32_32x32x16_f16(ah[2], b2, acc, 0, 0, 0);
            acc = __builtin_amdgcn_mfma_f32_32x32x16_f16(ah[3], b3, acc, 0, 0, 0);
            acc = __builtin_amdgcn_mfma_f32_32x32x16_f16(am[0], b0, acc, 0, 0, 0);
            acc = __builtin_amdgcn_mfma_f32_32x32x16_f16(am[1], b1, acc, 0, 0, 0);
            acc = __builtin_amdgcn_mfma_f32_32x32x16_f16(am[2], b2, acc, 0, 0, 0);
            acc = __builtin_amdgcn_mfma_f32_32x32x16_f16(am[3], b3, acc, 0, 0, 0);
            const int codeb = R * 128 + t * 32 + col;
            #pragma unroll
            for (int i = 0; i < 16; ++i) {
                if (acc[i] > best[i]) { best[i] = acc[i]; bcode[i] = codeb; }
            }
        }
        __syncthreads();
        #pragma unroll
        for (int t = 0; t < 4; ++t) nhck[t] = nhck_n[t];
    }

    // cross-lane argmax over the 32 code columns (xor<32 stays within half-wave)
    #pragma unroll
    for (int off = 1; off < 32; off <<= 1) {
        #pragma unroll
        for (int i = 0; i < 16; ++i) {
            float ow = __shfl_xor(best[i], off, 64);
            int oc = __shfl_xor(bcode[i], off, 64);
            if (ow > best[i] || (ow == best[i] && oc < bcode[i])) {
                best[i] = ow; bcode[i] = oc;
            }
        }
    }
    // publish per-row winner: packed (ord(w)<<32 | 8191-code); atomicMax merges
    // the KSPLIT chunks. Ties -> larger (8191-code) -> smaller global code,
    // matching the reference's first-index argmin.
    if (col == 0) {
        const int rbase = blockIdx.x * 256 + wave * 32 + 4 * h;
        #pragma unroll
        for (int i = 0; i < 16; ++i) {
            int row = rbase + (i & 3) + 8 * (i >> 2);
            unsigned u = __float_as_uint(best[i]);
            u = (u & 0x80000000u) ? ~u : (u | 0x80000000u);
            unsigned long long pk =
                ((unsigned long long)u << 32) |
                (unsigned)(8191 - (bcode[i] + kc * KC));
            atomicMax(&packed[row], pk);
        }
    }
}

// ---------------- K4: scatter (segment sums) + counts ----------------
__global__ __launch_bounds__(256) void k_scatter(
    const float* __restrict__ x, const float* __restrict__ stats,
    const unsigned long long* __restrict__ packed,
    float* __restrict__ dw, float* __restrict__ counts)
{
    const int t = blockIdx.x * 256 + threadIdx.x;
    const int row = t >> 6, col = t & 63;
    const int j = 8191 - (int)(packed[row] & 0xFFFFFFFFull);
    float xv = (x[(size_t)row * DIM + col] - stats[col]) * stats[64 + col];
    atomicAdd(&dw[(size_t)j * DIM + col], xv);
    if (col == 0) atomicAdd(&counts[j], 1.0f);
}

// ---------------- K5: epilogue ----------------
__global__ __launch_bounds__(256) void k_final(
    const float* __restrict__ emb, const float* __restrict__ cs,
    const float* __restrict__ dw, const float* __restrict__ counts,
    const float* __restrict__ stats, float* __restrict__ out)
{
    const int t = blockIdx.x * 256 + threadIdx.x; // over K*D
    const int k = t >> 6, d = t & 63;
    float csk = cs[k];
    float ns = csk * DECAYF + (1.f - DECAYF) * counts[k];
    float ne = (csk * emb[t] * DECAYF + (1.f - DECAYF) * dw[t]) / ns;
    out[KD + t] = ne;
    out[t] = ne * stats[128 + d] + stats[d];
    if (d == 0) out[2 * KD + k] = ns;
}

extern "C" void kernel_launch(void* const* d_in, const int* in_sizes, int n_in,
                              void* d_out, int out_size, void* d_ws, size_t ws_size,
                              hipStream_t stream)
{
    const float* x   = (const float*)d_in[0];
    const float* emb = (const float*)d_in[1];
    const float* cs  = (const float*)d_in[2];
    float* out = (float*)d_out;
    float* ws  = (float*)d_ws;

    float* stats  = ws + WS_STATS;
    float* nhck   = ws + WS_NHCK;
    half8* ebuf   = (half8*)(ws + WS_EBUF);
    float* psum   = ws + WS_PSUM;
    float* psq    = ws + WS_PSQ;
    unsigned long long* packed = (unsigned long long*)(ws + WS_PACKED);
    float* dw     = ws + WS_DW;
    float* counts = ws + WS_COUNTS;

    // zero packed + dw + counts (contiguous) in one shot
    hipMemsetAsync(ws + WS_PACKED, 0,
                   (size_t)(131072 + KD + KCODES) * sizeof(float), stream);

    k_colstats_partial<<<256, 256, 0, stream>>>(x, psum, psq);
    k_colstats_final<<<1, 64, 0, stream>>>(psum, psq, stats);
    k_prep<<<256, 256, 0, stream>>>(emb, ebuf, nhck);
    dim3 g3(NROWS / 256, KSPLIT);
    k_argmin32<<<g3, 512, 0, stream>>>(x, ebuf, nhck, stats, packed);
    k_scatter<<<(NROWS * DIM) / 256, 256, 0, stream>>>(x, stats, packed, dw, counts);
    k_final<<<KD / 256, 256, 0, stream>>>(emb, cs, dw, counts, stats, out);
}

// Round 7
// 172.579 us; speedup vs baseline: 1.3476x; 1.3476x over previous
//
#include <hip/hip_runtime.h>

#define NROWS 65536
#define DIM 64
#define KCODES 8192
#define DECAYF 0.99f
#define EPSV 1e-5f
#define KD (KCODES * DIM)
#define KSPLIT 4
#define KC (KCODES / KSPLIT)   // 2048 codes per split chunk
#define ROUNDS (KC / 128)      // 16 rounds x 128 codes (16 KB) per chunk

typedef _Float16 half8 __attribute__((ext_vector_type(8)));
typedef float f32x16 __attribute__((ext_vector_type(16)));

// ws layout (float offsets) — total ~3.9 MB
#define WS_STATS  0          // 256: mean[64], rstd[64], running_std[64]
#define WS_NHCK   256        // 8192: -0.5*||e_k||^2
#define WS_EBUF   8448       // 262144: 8192 codes x 64 dims f16 (1 MB), staged layout
#define WS_PSUM   270592     // 16384
#define WS_PSQ    286976     // 16384
#define WS_PACKED 303360     // 131072 floats = 65536 u64 (key<<32 | 8191-code)
#define WS_DW     434432     // 8192*64
#define WS_COUNTS 958720     // 8192  (PACKED..COUNTS contiguous: single memset)

// ---------------- K1a: per-block column partial sums ----------------
__global__ __launch_bounds__(256) void k_colstats_partial(
    const float* __restrict__ x, float* __restrict__ psum, float* __restrict__ psq)
{
    const int wave = threadIdx.x >> 6;
    const int col  = threadIdx.x & 63;
    const int base = blockIdx.x * 256;
    float s = 0.f, q = 0.f;
    #pragma unroll 4
    for (int i = 0; i < 64; ++i) {
        int r = base + i * 4 + wave;
        float v = x[(size_t)r * DIM + col];
        s += v;
        q += v * v;
    }
    __shared__ float ls[4][64];
    __shared__ float lq[4][64];
    ls[wave][col] = s;
    lq[wave][col] = q;
    __syncthreads();
    if (threadIdx.x < 64) {
        psum[blockIdx.x * 64 + col] = ls[0][col] + ls[1][col] + ls[2][col] + ls[3][col];
        psq[blockIdx.x * 64 + col]  = lq[0][col] + lq[1][col] + lq[2][col] + lq[3][col];
    }
}

// ---------------- K1b: finalize stats ----------------
__global__ void k_colstats_final(const float* __restrict__ psum,
                                 const float* __restrict__ psq,
                                 float* __restrict__ stats)
{
    const int col = threadIdx.x; // 64 threads
    float s = 0.f, q = 0.f;
    for (int i = 0; i < 256; ++i) {
        s += psum[i * 64 + col];
        q += psq[i * 64 + col];
    }
    const float n = (float)NROWS;
    float mean = s / n;
    float var = q / n - mean * mean;
    if (var < 0.f) var = 0.f;
    stats[col]       = mean;
    stats[64 + col]  = 1.0f / sqrtf(var + EPSV);
    stats[128 + col] = sqrtf(var * (n / (n - 1.0f)) + EPSV);
}

// ---------------- K2: prep emb (f16 centered plane, staged layout) + nhck --
// ebuf layout (half8 units): idx = R128*1024 + t*256 + c*64 + h*32 + col
//   code = R128*128 + t*32 + col ; element dims = c*16 + h*8 + j
__global__ __launch_bounds__(256) void k_prep(const float* __restrict__ emb,
                                              half8* __restrict__ ebuf,
                                              float* __restrict__ nhck)
{
    const int tid = blockIdx.x * 256 + threadIdx.x;   // 65536 = 8192 codes * 8
    const int code = tid >> 3, sub = tid & 7;
    const int c = sub >> 1, h = sub & 1;
    const int d0 = c * 16 + h * 8;
    const float* e = emb + (size_t)code * DIM + d0;
    float4 a = *(const float4*)e;
    float4 b = *(const float4*)(e + 4);
    float f[8] = {a.x, a.y, a.z, a.w, b.x, b.y, b.z, b.w};
    half8 hh;
    float ssq = 0.f;
    #pragma unroll
    for (int i = 0; i < 8; ++i) {
        hh[i] = (_Float16)(f[i] - 0.5f);   // centered: halves f16 quantization err
        ssq += f[i] * f[i];
    }
    #pragma unroll
    for (int o = 1; o < 8; o <<= 1) ssq += __shfl_xor(ssq, o, 64);
    if (sub == 0) nhck[code] = -0.5f * ssq;
    const int R = code >> 7, t = (code >> 5) & 3, col = code & 31;
    ebuf[(size_t)R * 1024 + t * 256 + c * 64 + h * 32 + col] = hh;
}

// ---------------- K3: 32x32 MFMA distance argmin ----------------
__device__ __forceinline__ void gload16(const void* g, void* l)
{
    __builtin_amdgcn_global_load_lds(
        (const __attribute__((address_space(1))) void*)g,
        (__attribute__((address_space(3))) void*)l, 16, 0, 0);
}

// 256 thr = 4 waves; wave owns 32 rows; block = 128 rows x KC codes.
// grid = (NROWS/128, KSPLIT) = 2048 blocks. Single f16 plane (x residual
// dropped: halves MFMA demand; score noise ~doubles, still << threshold).
// Maximizes w = f16(xn).f16(e-0.5) + nhck (== argmin dist).
// NOTE: 256-thr blocks, VGPR<=64: round-6 showed 512-thr pushed VGPR to 68,
// crossing the 64-reg occupancy cliff (waves/SIMD 8->4) and regressed.
__global__ __launch_bounds__(256, 4) void k_argmin32(
    const float* __restrict__ x, const half8* __restrict__ ebuf,
    const float* __restrict__ nhckg, const float* __restrict__ stats,
    unsigned long long* __restrict__ packed)
{
    __shared__ half8 smem[2048];   // 32 KB: 2 x 16 KB rounds

    const int lane = threadIdx.x & 63;
    const int wave = threadIdx.x >> 6;
    const int kc = blockIdx.y;
    const int col = lane & 31, h = lane >> 5;
    const int myrow = blockIdx.x * 128 + wave * 32 + col;

    // ---- A fragments: single f16 plane of normalized row ----
    half8 ah[4];
    {
        const float* xr = x + (size_t)myrow * DIM + h * 8;
        #pragma unroll
        for (int c = 0; c < 4; ++c) {
            float4 v0  = *(const float4*)(xr + c * 16);
            float4 v1  = *(const float4*)(xr + c * 16 + 4);
            float4 mu0 = *(const float4*)(stats + h * 8 + c * 16);
            float4 mu1 = *(const float4*)(stats + h * 8 + c * 16 + 4);
            float4 sg0 = *(const float4*)(stats + 64 + h * 8 + c * 16);
            float4 sg1 = *(const float4*)(stats + 64 + h * 8 + c * 16 + 4);
            ah[c][0] = (_Float16)((v0.x - mu0.x) * sg0.x);
            ah[c][1] = (_Float16)((v0.y - mu0.y) * sg0.y);
            ah[c][2] = (_Float16)((v0.z - mu0.z) * sg0.z);
            ah[c][3] = (_Float16)((v0.w - mu0.w) * sg0.w);
            ah[c][4] = (_Float16)((v1.x - mu1.x) * sg1.x);
            ah[c][5] = (_Float16)((v1.y - mu1.y) * sg1.y);
            ah[c][6] = (_Float16)((v1.z - mu1.z) * sg1.z);
            ah[c][7] = (_Float16)((v1.w - mu1.w) * sg1.w);
        }
    }

    float best[16];
    int bcode[16];
    #pragma unroll
    for (int i = 0; i < 16; ++i) { best[i] = -3.4e38f; bcode[i] = 0; }

    const half8* esrc = ebuf + (size_t)kc * (KC * 8);   // 8 half8 per code
    const float* ckb = nhckg + kc * KC;

    // prologue stage (256 thr x 16 B x 4 = 16 KB) + first-round ck prefetch
    {
        const char* src = (const char*)esrc + threadIdx.x * 16;
        char* dst = (char*)smem + threadIdx.x * 16;
        #pragma unroll
        for (int i = 0; i < 4; ++i) gload16(src + i * 4096, dst + i * 4096);
    }
    float nhck[4];
    #pragma unroll
    for (int t = 0; t < 4; ++t) nhck[t] = ckb[t * 32 + col];
    __syncthreads();

    for (int R = 0; R < ROUNDS; ++R) {
        const int buf = R & 1;
        float nhck_n[4] = {0.f, 0.f, 0.f, 0.f};
        if (R < ROUNDS - 1) {
            const char* src = (const char*)esrc + (size_t)(R + 1) * 16384 + threadIdx.x * 16;
            char* dst = (char*)smem + (buf ^ 1) * 16384 + threadIdx.x * 16;
            #pragma unroll
            for (int i = 0; i < 4; ++i) gload16(src + i * 4096, dst + i * 4096);
            #pragma unroll
            for (int t = 0; t < 4; ++t) nhck_n[t] = ckb[(R + 1) * 128 + t * 32 + col];
        }

        const half8* sb = smem + buf * 1024 + lane;
        #pragma unroll
        for (int t = 0; t < 4; ++t) {
            half8 b0 = sb[t * 256];
            half8 b1 = sb[t * 256 + 64];
            half8 b2 = sb[t * 256 + 128];
            half8 b3 = sb[t * 256 + 192];
            f32x16 acc;
            #pragma unroll
            for (int i = 0; i < 16; ++i) acc[i] = nhck[t];
            __builtin_amdgcn_s_setprio(1);
            acc = __builtin_amdgcn_mfma_f32_32x32x16_f16(ah[0], b0, acc, 0, 0, 0);
            acc = __builtin_amdgcn_mfma_f32_32x32x16_f16(ah[1], b1, acc, 0, 0, 0);
            acc = __builtin_amdgcn_mfma_f32_32x32x16_f16(ah[2], b2, acc, 0, 0, 0);
            acc = __builtin_amdgcn_mfma_f32_32x32x16_f16(ah[3], b3, acc, 0, 0, 0);
            __builtin_amdgcn_s_setprio(0);
            const int codeb = R * 128 + t * 32 + col;
            #pragma unroll
            for (int i = 0; i < 16; ++i) {
                if (acc[i] > best[i]) { best[i] = acc[i]; bcode[i] = codeb; }
            }
        }
        __syncthreads();
        #pragma unroll
        for (int t = 0; t < 4; ++t) nhck[t] = nhck_n[t];
    }

    // cross-lane argmax over the 32 code columns (xor<32 stays within half-wave)
    #pragma unroll
    for (int off = 1; off < 32; off <<= 1) {
        #pragma unroll
        for (int i = 0; i < 16; ++i) {
            float ow = __shfl_xor(best[i], off, 64);
            int oc = __shfl_xor(bcode[i], off, 64);
            if (ow > best[i] || (ow == best[i] && oc < bcode[i])) {
                best[i] = ow; bcode[i] = oc;
            }
        }
    }
    // publish per-row winner: packed (ord(w)<<32 | 8191-code); atomicMax merges
    // the KSPLIT chunks. Ties -> larger (8191-code) -> smaller global code,
    // matching the reference's first-index argmin.
    if (col == 0) {
        const int rbase = blockIdx.x * 128 + wave * 32 + 4 * h;
        #pragma unroll
        for (int i = 0; i < 16; ++i) {
            int row = rbase + (i & 3) + 8 * (i >> 2);
            unsigned u = __float_as_uint(best[i]);
            u = (u & 0x80000000u) ? ~u : (u | 0x80000000u);
            unsigned long long pk =
                ((unsigned long long)u << 32) |
                (unsigned)(8191 - (bcode[i] + kc * KC));
            atomicMax(&packed[row], pk);
        }
    }
}

// ---------------- K4: scatter (segment sums) + counts ----------------
__global__ __launch_bounds__(256) void k_scatter(
    const float* __restrict__ x, const float* __restrict__ stats,
    const unsigned long long* __restrict__ packed,
    float* __restrict__ dw, float* __restrict__ counts)
{
    const int t = blockIdx.x * 256 + threadIdx.x;
    const int row = t >> 6, col = t & 63;
    const int j = 8191 - (int)(packed[row] & 0xFFFFFFFFull);
    float xv = (x[(size_t)row * DIM + col] - stats[col]) * stats[64 + col];
    atomicAdd(&dw[(size_t)j * DIM + col], xv);
    if (col == 0) atomicAdd(&counts[j], 1.0f);
}

// ---------------- K5: epilogue ----------------
__global__ __launch_bounds__(256) void k_final(
    const float* __restrict__ emb, const float* __restrict__ cs,
    const float* __restrict__ dw, const float* __restrict__ counts,
    const float* __restrict__ stats, float* __restrict__ out)
{
    const int t = blockIdx.x * 256 + threadIdx.x; // over K*D
    const int k = t >> 6, d = t & 63;
    float csk = cs[k];
    float ns = csk * DECAYF + (1.f - DECAYF) * counts[k];
    float ne = (csk * emb[t] * DECAYF + (1.f - DECAYF) * dw[t]) / ns;
    out[KD + t] = ne;
    out[t] = ne * stats[128 + d] + stats[d];
    if (d == 0) out[2 * KD + k] = ns;
}

extern "C" void kernel_launch(void* const* d_in, const int* in_sizes, int n_in,
                              void* d_out, int out_size, void* d_ws, size_t ws_size,
                              hipStream_t stream)
{
    const float* x   = (const float*)d_in[0];
    const float* emb = (const float*)d_in[1];
    const float* cs  = (const float*)d_in[2];
    float* out = (float*)d_out;
    float* ws  = (float*)d_ws;

    float* stats  = ws + WS_STATS;
    float* nhck   = ws + WS_NHCK;
    half8* ebuf   = (half8*)(ws + WS_EBUF);
    float* psum   = ws + WS_PSUM;
    float* psq    = ws + WS_PSQ;
    unsigned long long* packed = (unsigned long long*)(ws + WS_PACKED);
    float* dw     = ws + WS_DW;
    float* counts = ws + WS_COUNTS;

    // zero packed + dw + counts (contiguous) in one shot
    hipMemsetAsync(ws + WS_PACKED, 0,
                   (size_t)(131072 + KD + KCODES) * sizeof(float), stream);

    k_colstats_partial<<<256, 256, 0, stream>>>(x, psum, psq);
    k_colstats_final<<<1, 64, 0, stream>>>(psum, psq, stats);
    k_prep<<<256, 256, 0, stream>>>(emb, ebuf, nhck);
    dim3 g3(NROWS / 128, KSPLIT);
    k_argmin32<<<g3, 256, 0, stream>>>(x, ebuf, nhck, stats, packed);
    k_scatter<<<(NROWS * DIM) / 256, 256, 0, stream>>>(x, stats, packed, dw, counts);
    k_final<<<KD / 256, 256, 0, stream>>>(emb, cs, dw, counts, stats, out);
}

// Round 8
// 157.881 us; speedup vs baseline: 1.4730x; 1.0931x over previous
//
#include <hip/hip_runtime.h>

#define NROWS 65536
#define DIM 64
#define KCODES 8192
#define DECAYF 0.99f
#define EPSV 1e-5f
#define KD (KCODES * DIM)
#define KSPLIT 4
#define KC (KCODES / KSPLIT)   // 2048 codes per split chunk
#define ROUNDS (KC / 128)      // 16 rounds x 128 codes (16 KB) per chunk

typedef _Float16 half8 __attribute__((ext_vector_type(8)));
typedef float f32x16 __attribute__((ext_vector_type(16)));

// ws layout (float offsets) — total ~3.6 MB
#define WS_STATS  0          // 256: mean[64], rstd[64], running_std[64]
#define WS_NHCK   256        // 8192: 10.6875 - 0.5*||e_k||^2 (centered)
#define WS_EBUF   8448       // 262144: 8192 codes x 64 dims f16 (1 MB), staged layout
#define WS_PSUM   270592     // 16384
#define WS_PSQ    286976     // 16384
#define WS_PACKED 303360     // 65536 u32: flip(score w/ key in low 13 bits)
#define WS_DW     368896     // 8192*64
#define WS_COUNTS 893184     // 8192  (PACKED..COUNTS contiguous: single memset)

// ---------------- K1a: per-block column partial sums ----------------
__global__ __launch_bounds__(256) void k_colstats_partial(
    const float* __restrict__ x, float* __restrict__ psum, float* __restrict__ psq)
{
    const int wave = threadIdx.x >> 6;
    const int col  = threadIdx.x & 63;
    const int base = blockIdx.x * 256;
    float s = 0.f, q = 0.f;
    #pragma unroll 4
    for (int i = 0; i < 64; ++i) {
        int r = base + i * 4 + wave;
        float v = x[(size_t)r * DIM + col];
        s += v;
        q += v * v;
    }
    __shared__ float ls[4][64];
    __shared__ float lq[4][64];
    ls[wave][col] = s;
    lq[wave][col] = q;
    __syncthreads();
    if (threadIdx.x < 64) {
        psum[blockIdx.x * 64 + col] = ls[0][col] + ls[1][col] + ls[2][col] + ls[3][col];
        psq[blockIdx.x * 64 + col]  = lq[0][col] + lq[1][col] + lq[2][col] + lq[3][col];
    }
}

// ---------------- K1b: finalize stats ----------------
__global__ void k_colstats_final(const float* __restrict__ psum,
                                 const float* __restrict__ psq,
                                 float* __restrict__ stats)
{
    const int col = threadIdx.x; // 64 threads
    float s = 0.f, q = 0.f;
    for (int i = 0; i < 256; ++i) {
        s += psum[i * 64 + col];
        q += psq[i * 64 + col];
    }
    const float n = (float)NROWS;
    float mean = s / n;
    float var = q / n - mean * mean;
    if (var < 0.f) var = 0.f;
    stats[col]       = mean;
    stats[64 + col]  = 1.0f / sqrtf(var + EPSV);
    stats[128 + col] = sqrtf(var * (n / (n - 1.0f)) + EPSV);
}

// ---------------- K2: prep emb (f16 centered plane, staged layout) + nhck --
// ebuf layout (half8 units): idx = R128*1024 + t*256 + c*64 + h*32 + col
//   code = R128*128 + t*32 + col ; element dims = c*16 + h*8 + j
__global__ __launch_bounds__(256) void k_prep(const float* __restrict__ emb,
                                              half8* __restrict__ ebuf,
                                              float* __restrict__ nhck)
{
    const int tid = blockIdx.x * 256 + threadIdx.x;   // 65536 = 8192 codes * 8
    const int code = tid >> 3, sub = tid & 7;
    const int c = sub >> 1, h = sub & 1;
    const int d0 = c * 16 + h * 8;
    const float* e = emb + (size_t)code * DIM + d0;
    float4 a = *(const float4*)e;
    float4 b = *(const float4*)(e + 4);
    float f[8] = {a.x, a.y, a.z, a.w, b.x, b.y, b.z, b.w};
    half8 hh;
    float ssq = 0.f;
    #pragma unroll
    for (int i = 0; i < 8; ++i) {
        hh[i] = (_Float16)(f[i] - 0.5f);   // centered: halves f16 quantization err
        ssq += f[i] * f[i];
    }
    #pragma unroll
    for (int o = 1; o < 8; o <<= 1) ssq += __shfl_xor(ssq, o, 64);
    // centered score bias: keeps |score| small so the low-13-bit key
    // corruption (bfi-max trick) stays ~1e-3
    if (sub == 0) nhck[code] = 10.6875f - 0.5f * ssq;
    const int R = code >> 7, t = (code >> 5) & 3, col = code & 31;
    ebuf[(size_t)R * 1024 + t * 256 + c * 64 + h * 32 + col] = hh;
}

// ---------------- K3: 32x32 MFMA distance argmin ----------------
__device__ __forceinline__ void gload16(const void* g, void* l)
{
    __builtin_amdgcn_global_load_lds(
        (const __attribute__((address_space(1))) void*)g,
        (__attribute__((address_space(3))) void*)l, 16, 0, 0);
}

// 256 thr = 4 waves; wave owns 32 rows; block = 128 rows x KC codes.
// grid = (NROWS/128, KSPLIT). Single f16 plane.
// Maximizes w = f16(xn).f16(e-0.5) + nhck' (== argmin dist, score centered).
// Select uses the bfi-max trick: low 13 mantissa bits of the running best
// carry key = 8191-code (larger key = smaller code wins ties for w>=0).
__global__ __launch_bounds__(256) void k_argmin32(
    const float* __restrict__ x, const half8* __restrict__ ebuf,
    const float* __restrict__ nhckg, const float* __restrict__ stats,
    unsigned* __restrict__ packed)
{
    __shared__ half8 smem[2048];   // 32 KB: 2 x 16 KB rounds

    const int lane = threadIdx.x & 63;
    const int wave = threadIdx.x >> 6;
    const int kc = blockIdx.y;
    const int col = lane & 31, h = lane >> 5;
    const int myrow = blockIdx.x * 128 + wave * 32 + col;

    // ---- A fragments: single f16 plane of normalized row ----
    half8 ah[4];
    {
        const float* xr = x + (size_t)myrow * DIM + h * 8;
        #pragma unroll
        for (int c = 0; c < 4; ++c) {
            float4 v0  = *(const float4*)(xr + c * 16);
            float4 v1  = *(const float4*)(xr + c * 16 + 4);
            float4 mu0 = *(const float4*)(stats + h * 8 + c * 16);
            float4 mu1 = *(const float4*)(stats + h * 8 + c * 16 + 4);
            float4 sg0 = *(const float4*)(stats + 64 + h * 8 + c * 16);
            float4 sg1 = *(const float4*)(stats + 64 + h * 8 + c * 16 + 4);
            ah[c][0] = (_Float16)((v0.x - mu0.x) * sg0.x);
            ah[c][1] = (_Float16)((v0.y - mu0.y) * sg0.y);
            ah[c][2] = (_Float16)((v0.z - mu0.z) * sg0.z);
            ah[c][3] = (_Float16)((v0.w - mu0.w) * sg0.w);
            ah[c][4] = (_Float16)((v1.x - mu1.x) * sg1.x);
            ah[c][5] = (_Float16)((v1.y - mu1.y) * sg1.y);
            ah[c][6] = (_Float16)((v1.z - mu1.z) * sg1.z);
            ah[c][7] = (_Float16)((v1.w - mu1.w) * sg1.w);
        }
    }

    float best[16];
    #pragma unroll
    for (int i = 0; i < 16; ++i) best[i] = -3.4e38f;

    const half8* esrc = ebuf + (size_t)kc * (KC * 8);   // 8 half8 per code
    const float* ckb = nhckg + kc * KC;

    // prologue stage (256 thr x 16 B x 4 = 16 KB) + first-round ck prefetch
    {
        const char* src = (const char*)esrc + threadIdx.x * 16;
        char* dst = (char*)smem + threadIdx.x * 16;
        #pragma unroll
        for (int i = 0; i < 4; ++i) gload16(src + i * 4096, dst + i * 4096);
    }
    float nhck[4];
    #pragma unroll
    for (int t = 0; t < 4; ++t) nhck[t] = ckb[t * 32 + col];
    __syncthreads();

    for (int R = 0; R < ROUNDS; ++R) {
        const int buf = R & 1;
        float nhck_n[4] = {0.f, 0.f, 0.f, 0.f};
        if (R < ROUNDS - 1) {
            const char* src = (const char*)esrc + (size_t)(R + 1) * 16384 + threadIdx.x * 16;
            char* dst = (char*)smem + (buf ^ 1) * 16384 + threadIdx.x * 16;
            #pragma unroll
            for (int i = 0; i < 4; ++i) gload16(src + i * 4096, dst + i * 4096);
            #pragma unroll
            for (int t = 0; t < 4; ++t) nhck_n[t] = ckb[(R + 1) * 128 + t * 32 + col];
        }

        const half8* sb = smem + buf * 1024 + lane;
        #pragma unroll
        for (int t = 0; t < 4; ++t) {
            half8 b0 = sb[t * 256];
            half8 b1 = sb[t * 256 + 64];
            half8 b2 = sb[t * 256 + 128];
            half8 b3 = sb[t * 256 + 192];
            f32x16 acc;
            #pragma unroll
            for (int i = 0; i < 16; ++i) acc[i] = nhck[t];
            __builtin_amdgcn_s_setprio(1);
            acc = __builtin_amdgcn_mfma_f32_32x32x16_f16(ah[0], b0, acc, 0, 0, 0);
            acc = __builtin_amdgcn_mfma_f32_32x32x16_f16(ah[1], b1, acc, 0, 0, 0);
            acc = __builtin_amdgcn_mfma_f32_32x32x16_f16(ah[2], b2, acc, 0, 0, 0);
            acc = __builtin_amdgcn_mfma_f32_32x32x16_f16(ah[3], b3, acc, 0, 0, 0);
            __builtin_amdgcn_s_setprio(0);
            // key = 8191 - global code for this lane's column
            const unsigned key = (unsigned)(8191 - (kc * KC + R * 128 + t * 32 + col));
            #pragma unroll
            for (int i = 0; i < 16; ++i) {
                unsigned u = (__float_as_uint(acc[i]) & 0xFFFFE000u) | key;
                best[i] = fmaxf(best[i], __uint_as_float(u));
            }
        }
        __syncthreads();
        #pragma unroll
        for (int t = 0; t < 4; ++t) nhck[t] = nhck_n[t];
    }

    // cross-lane max over the 32 code columns (keys break ties -> no equals)
    #pragma unroll
    for (int off = 1; off < 32; off <<= 1) {
        #pragma unroll
        for (int i = 0; i < 16; ++i)
            best[i] = fmaxf(best[i], __shfl_xor(best[i], off, 64));
    }
    // publish per-row winner as sortable u32; atomicMax merges KSPLIT chunks.
    if (col == 0) {
        const int rbase = blockIdx.x * 128 + wave * 32 + 4 * h;
        #pragma unroll
        for (int i = 0; i < 16; ++i) {
            int row = rbase + (i & 3) + 8 * (i >> 2);
            unsigned u = __float_as_uint(best[i]);
            u = (u & 0x80000000u) ? ~u : (u | 0x80000000u);
            atomicMax(&packed[row], u);
        }
    }
}

// ---------------- K4: scatter (segment sums) + counts ----------------
__global__ __launch_bounds__(256) void k_scatter(
    const float* __restrict__ x, const float* __restrict__ stats,
    const unsigned* __restrict__ packed,
    float* __restrict__ dw, float* __restrict__ counts)
{
    const int t = blockIdx.x * 256 + threadIdx.x;
    const int row = t >> 6, col = t & 63;
    const unsigned v = packed[row];
    const unsigned key = (v & 0x80000000u) ? (v & 8191u) : (~v & 8191u);
    const int j = 8191 - (int)key;
    float xv = (x[(size_t)row * DIM + col] - stats[col]) * stats[64 + col];
    atomicAdd(&dw[(size_t)j * DIM + col], xv);
    if (col == 0) atomicAdd(&counts[j], 1.0f);
}

// ---------------- K5: epilogue ----------------
__global__ __launch_bounds__(256) void k_final(
    const float* __restrict__ emb, const float* __restrict__ cs,
    const float* __restrict__ dw, const float* __restrict__ counts,
    const float* __restrict__ stats, float* __restrict__ out)
{
    const int t = blockIdx.x * 256 + threadIdx.x; // over K*D
    const int k = t >> 6, d = t & 63;
    float csk = cs[k];
    float ns = csk * DECAYF + (1.f - DECAYF) * counts[k];
    float ne = (csk * emb[t] * DECAYF + (1.f - DECAYF) * dw[t]) / ns;
    out[KD + t] = ne;
    out[t] = ne * stats[128 + d] + stats[d];
    if (d == 0) out[2 * KD + k] = ns;
}

extern "C" void kernel_launch(void* const* d_in, const int* in_sizes, int n_in,
                              void* d_out, int out_size, void* d_ws, size_t ws_size,
                              hipStream_t stream)
{
    const float* x   = (const float*)d_in[0];
    const float* emb = (const float*)d_in[1];
    const float* cs  = (const float*)d_in[2];
    float* out = (float*)d_out;
    float* ws  = (float*)d_ws;

    float* stats  = ws + WS_STATS;
    float* nhck   = ws + WS_NHCK;
    half8* ebuf   = (half8*)(ws + WS_EBUF);
    float* psum   = ws + WS_PSUM;
    float* psq    = ws + WS_PSQ;
    unsigned* packed = (unsigned*)(ws + WS_PACKED);
    float* dw     = ws + WS_DW;
    float* counts = ws + WS_COUNTS;

    // zero packed + dw + counts (contiguous) in one shot
    hipMemsetAsync(ws + WS_PACKED, 0,
                   (size_t)(65536 + KD + KCODES) * sizeof(float), stream);

    k_colstats_partial<<<256, 256, 0, stream>>>(x, psum, psq);
    k_colstats_final<<<1, 64, 0, stream>>>(psum, psq, stats);
    k_prep<<<256, 256, 0, stream>>>(emb, ebuf, nhck);
    dim3 g3(NROWS / 128, KSPLIT);
    k_argmin32<<<g3, 256, 0, stream>>>(x, ebuf, nhck, stats, packed);
    k_scatter<<<(NROWS * DIM) / 256, 256, 0, stream>>>(x, stats, packed, dw, counts);
    k_final<<<KD / 256, 256, 0, stream>>>(emb, cs, dw, counts, stats, out);
}